// Round 2
// baseline (243.625 us; speedup 1.0000x reference)
//
#include <hip/hip_runtime.h>
#include <hip/hip_bf16.h>

#define B_ROWS 32768

typedef unsigned short u16;
typedef unsigned int u32;
typedef float f32x4 __attribute__((ext_vector_type(4)));
typedef __bf16 bf16x8 __attribute__((ext_vector_type(8)));
typedef unsigned short u16x8 __attribute__((ext_vector_type(8)));

__device__ __forceinline__ u16 f2bf(float f){
    union { float f; u32 u; } v; v.f = f;
    return (u16)((v.u + 0x7FFFu + ((v.u >> 16) & 1u)) >> 16);
}
__device__ __forceinline__ float bf2f(u16 h){
    union { u32 u; float f; } v; v.u = ((u32)h) << 16; return v.f;
}
// v_cvt_pk_bf16_f32: dst.lo = bf16(lo), dst.hi = bf16(hi), RNE
__device__ __forceinline__ u32 cvtpk(float lo, float hi){
    u32 r;
    asm("v_cvt_pk_bf16_f32 %0, %1, %2" : "=v"(r) : "v"(lo), "v"(hi));
    return r;
}

// ---------------- weight cast + transpose to [out_col][k] bf16 ----------------
__global__ void cast_weights_kernel(const float* __restrict__ proj_w,
                                    const float* __restrict__ exp_w1,
                                    const float* __restrict__ exp_w2,
                                    const float* __restrict__ pre_w,
                                    const float* __restrict__ gate_w,
                                    u16* __restrict__ pwT, u16* __restrict__ w1T,
                                    u16* __restrict__ w2T, u16* __restrict__ prwT,
                                    u16* __restrict__ gwT){
    int i = blockIdx.x * 256 + threadIdx.x;
    if (i < 294912){                       // proj_wT [3][128][768]
        int m = i / 98304, r = i % 98304;
        int p = r / 768, d = r % 768;
        pwT[i] = f2bf(proj_w[m*98304 + d*128 + p]);
    } else if (i < 688128){                // exp_w1T [8][128][384]
        int j = i - 294912;
        int e = j / 49152, r = j % 49152;
        int h = r / 384, k = r % 384;
        w1T[j] = f2bf(exp_w1[e*49152 + k*128 + h]);
    } else if (i < 819200){                // exp_w2T [8][128][128]
        int j = i - 688128;
        int e = j / 16384, r = j % 16384;
        int o = r / 128, k = r % 128;
        w2T[j] = f2bf(exp_w2[e*16384 + k*128 + o]);
    } else if (i < 827392){                // pre_wT [64][128]
        int j = i - 819200;
        int o = j / 128, k = j % 128;
        prwT[j] = f2bf(pre_w[k*64 + o]);
    } else if (i < 830464){                // gate_wT [8][384]
        int j = i - 827392;
        int e = j / 384, k = j % 384;
        gwT[j] = f2bf(gate_w[k*8 + e]);
    }
}

// ---------------- proj: x[b, m*128+p] = feat_m[b,:] @ proj_w[m] + proj_b ------
// grid (B/64, 3), 256 threads = 4 waves (2x2), tile 64x128, BK=64, reg-dbuf.
__global__ __launch_bounds__(256) void proj_kernel(
    const float* __restrict__ ft, const float* __restrict__ fa, const float* __restrict__ fv,
    const u16* __restrict__ pwT, const float* __restrict__ proj_b,
    u16* __restrict__ xq)
{
    // As [64][72] bf16, Bs [128][72] bf16. Row stride 144B -> 144/16=9 (odd)
    // so 16B-slot index (9*r + s) mod 8 covers all 8 slots: <=2-way alias (free).
    __shared__ u16 smem[64*72 + 128*72];
    u16 (*As)[72] = (u16(*)[72])smem;
    u16 (*Bs)[72] = (u16(*)[72])(smem + 64*72);

    const int m = blockIdx.y;
    const float* feat = (m == 0) ? ft : (m == 1) ? fa : fv;
    const int row0 = blockIdx.x * 64;
    const int tid  = threadIdx.x;
    const int lane = tid & 63, wid = tid >> 6;
    const int wr = wid >> 1, wc = wid & 1;
    const int lr = lane & 15, q = lane >> 4, lk8 = q * 8, r4 = q * 4;

    // A staging: pass p: row = p*16 + (tid>>4), col = (tid&15)*4  (float4)
    const float* aG = feat + (size_t)(row0 + (tid >> 4)) * 768 + (tid & 15) * 4;
    // B staging: pass p: col = p*32 + (tid>>3), k = (tid&7)*8      (uint4, bf16)
    const u16* bG = pwT + (size_t)m * 98304 + (size_t)(tid >> 3) * 768 + (tid & 7) * 8;

    float4 ar[4]; uint4 br[4];
    #pragma unroll
    for (int p = 0; p < 4; p++) ar[p] = *(const float4*)(aG + (size_t)p * 16 * 768);
    #pragma unroll
    for (int p = 0; p < 4; p++) br[p] = *(const uint4*)(bG + (size_t)p * 32 * 768);

    f32x4 acc[2][4];
    #pragma unroll
    for (int i = 0; i < 2; i++)
        #pragma unroll
        for (int j = 0; j < 4; j++) acc[i][j] = {0.f, 0.f, 0.f, 0.f};

    const int ra = tid >> 4, ca = (tid & 15) * 4;
    const int rb = tid >> 3, cb = (tid & 7) * 8;

    for (int kt = 0; kt < 768; kt += 64){
        if (kt) __syncthreads();
        #pragma unroll
        for (int p = 0; p < 4; p++){
            u32 lo = cvtpk(ar[p].x, ar[p].y), hi = cvtpk(ar[p].z, ar[p].w);
            uint2 pk = {lo, hi};
            *(uint2*)&As[p*16 + ra][ca] = pk;
        }
        #pragma unroll
        for (int p = 0; p < 4; p++) *(uint4*)&Bs[p*32 + rb][cb] = br[p];
        __syncthreads();
        if (kt + 64 < 768){
            #pragma unroll
            for (int p = 0; p < 4; p++) ar[p] = *(const float4*)(aG + kt + 64 + (size_t)p * 16 * 768);
            #pragma unroll
            for (int p = 0; p < 4; p++) br[p] = *(const uint4*)(bG + kt + 64 + (size_t)p * 32 * 768);
        }
        #pragma unroll
        for (int ks = 0; ks < 2; ks++){
            bf16x8 af[2], bfr[4];
            #pragma unroll
            for (int mi = 0; mi < 2; mi++) af[mi]  = *(const bf16x8*)&As[wr*32 + mi*16 + lr][ks*32 + lk8];
            #pragma unroll
            for (int ni = 0; ni < 4; ni++) bfr[ni] = *(const bf16x8*)&Bs[wc*64 + ni*16 + lr][ks*32 + lk8];
            #pragma unroll
            for (int mi = 0; mi < 2; mi++)
                #pragma unroll
                for (int ni = 0; ni < 4; ni++)
                    acc[mi][ni] = __builtin_amdgcn_mfma_f32_16x16x32_bf16(af[mi], bfr[ni], acc[mi][ni], 0, 0, 0);
        }
    }
    // epilogue: stage bf16 tile in LDS, then coalesced 64B/lane stores
    __syncthreads();
    u16 (*Os)[136] = (u16(*)[136])smem;
    #pragma unroll
    for (int mi = 0; mi < 2; mi++)
        #pragma unroll
        for (int ni = 0; ni < 4; ni++){
            int col = wc*64 + ni*16 + lr;
            float bias = proj_b[m*128 + col];
            #pragma unroll
            for (int j = 0; j < 4; j++)
                Os[wr*32 + mi*16 + r4 + j][col] = f2bf(acc[mi][ni][j] + bias);
        }
    __syncthreads();
    {
        int row = tid >> 2, cg = (tid & 3) * 32;
        u16* dst = xq + (size_t)(row0 + row) * 384 + m*128 + cg;
        #pragma unroll
        for (int i = 0; i < 4; i++)
            *(uint4*)(dst + i*8) = *(uint4*)&Os[row][cg + i*8];
    }
}

// ---------------- fused gate + experts + pre + head ---------------------------
// grid (B/64), 256 threads = 4 waves (2x2). LDS ~78KB -> 2 blocks/CU.
__global__ __launch_bounds__(256) void moe_kernel(
    const u16* __restrict__ xq,
    const u16* __restrict__ w1T, const u16* __restrict__ w2T, const u16* __restrict__ prwT,
    const u16* __restrict__ gwT, const float* __restrict__ gate_b,
    const float* __restrict__ exp_b1, const float* __restrict__ exp_b2,
    const float* __restrict__ pre_b, const float* __restrict__ head_w, const float* __restrict__ head_b,
    float* __restrict__ out)
{
    __shared__ u16  Xs[64][392];   // x tile, full K=384 (+8 pad)
    __shared__ u16  Ws[128][40];   // per-K-step weight staging
    __shared__ u16  Hs[64][136];   // h tile / fused tile (+8 pad)
    __shared__ float GW[64][8];    // gate weights

    const int row0 = blockIdx.x * 64;
    const int tid  = threadIdx.x;
    const int lane = tid & 63, wid = tid >> 6;
    const int wr = wid >> 1, wc = wid & 1;
    const int lr = lane & 15, lk8 = (lane >> 4) * 8, r4 = (lane >> 4) * 4;
    const int scol = tid >> 1, sh = (tid & 1) * 16;

    {   // load x tile: 4 threads per row, 96 cols each
        const int xr = tid >> 2, xc = (tid & 3) * 96;
        const u16* xg = xq + (size_t)(row0 + xr) * 384 + xc;
        #pragma unroll
        for (int i = 0; i < 12; i++)
            *(uint4*)&Xs[xr][xc + i*8] = *(const uint4*)(xg + i*8);
    }
    __syncthreads();

    // ---- gate logits + softmax ----
    for (int task = tid; task < 512; task += 256){
        int r = task >> 3, e = task & 7;
        float s = gate_b[e];
        const u16* gw = gwT + e * 384;
        for (int k = 0; k < 384; k += 8){
            u16x8 xv = *(const u16x8*)&Xs[r][k];
            u16x8 wv = *(const u16x8*)(gw + k);
            #pragma unroll
            for (int j = 0; j < 8; j++) s += bf2f(xv[j]) * bf2f(wv[j]);
        }
        GW[r][e] = s;
    }
    __syncthreads();
    if (tid < 64){
        float v[8], mx = -1e30f;
        #pragma unroll
        for (int e = 0; e < 8; e++){ v[e] = GW[tid][e]; mx = fmaxf(mx, v[e]); }
        float sum = 0.f;
        #pragma unroll
        for (int e = 0; e < 8; e++){ v[e] = __expf(v[e] - mx); sum += v[e]; }
        float inv = 1.f / sum;
        #pragma unroll
        for (int e = 0; e < 8; e++) GW[tid][e] = v[e] * inv;
    }
    // (GW consumed only after multiple barriers below)

    f32x4 fus[2][4];
    #pragma unroll
    for (int i = 0; i < 2; i++)
        #pragma unroll
        for (int j = 0; j < 4; j++) fus[i][j] = {0.f, 0.f, 0.f, 0.f};

    for (int e = 0; e < 8; e++){
        // ---- h = relu(x @ w1_e + b1) : [64x384]x[384x128] ----
        f32x4 acc[2][4];
        #pragma unroll
        for (int i = 0; i < 2; i++)
            #pragma unroll
            for (int j = 0; j < 4; j++) acc[i][j] = {0.f, 0.f, 0.f, 0.f};
        const u16* wg = w1T + (size_t)e*49152 + (size_t)scol*384 + sh;
        uint4 c0 = *(const uint4*)(wg);
        uint4 c1 = *(const uint4*)(wg + 8);
        for (int kt = 0; kt < 384; kt += 32){
            __syncthreads();
            *(uint4*)&Ws[scol][sh]     = c0;
            *(uint4*)&Ws[scol][sh + 8] = c1;
            __syncthreads();
            if (kt + 32 < 384){
                c0 = *(const uint4*)(wg + kt + 32);
                c1 = *(const uint4*)(wg + kt + 40);
            }
            bf16x8 af[2], bfr[4];
            #pragma unroll
            for (int mi = 0; mi < 2; mi++) af[mi]  = *(const bf16x8*)&Xs[wr*32 + mi*16 + lr][kt + lk8];
            #pragma unroll
            for (int ni = 0; ni < 4; ni++) bfr[ni] = *(const bf16x8*)&Ws[wc*64 + ni*16 + lr][lk8];
            #pragma unroll
            for (int mi = 0; mi < 2; mi++)
                #pragma unroll
                for (int ni = 0; ni < 4; ni++)
                    acc[mi][ni] = __builtin_amdgcn_mfma_f32_16x16x32_bf16(af[mi], bfr[ni], acc[mi][ni], 0, 0, 0);
        }
        // write h (relu, bf16) — Hs reads of previous expert are barriers behind us
        #pragma unroll
        for (int mi = 0; mi < 2; mi++)
            #pragma unroll
            for (int ni = 0; ni < 4; ni++){
                int col = wc*64 + ni*16 + lr;
                float b1v = exp_b1[e*128 + col];
                #pragma unroll
                for (int j = 0; j < 4; j++){
                    int row = wr*32 + mi*16 + r4 + j;
                    Hs[row][col] = f2bf(fmaxf(acc[mi][ni][j] + b1v, 0.f));
                }
            }
        // ---- eo = h @ w2_e + b2 : [64x128]x[128x128] ----
        f32x4 acc2[2][4];
        #pragma unroll
        for (int i = 0; i < 2; i++)
            #pragma unroll
            for (int j = 0; j < 4; j++) acc2[i][j] = {0.f, 0.f, 0.f, 0.f};
        const u16* w2g = w2T + (size_t)e*16384 + (size_t)scol*128 + sh;
        uint4 d0 = *(const uint4*)(w2g);
        uint4 d1 = *(const uint4*)(w2g + 8);
        for (int kt = 0; kt < 128; kt += 32){
            __syncthreads();   // also orders Hs writes before Hs reads
            *(uint4*)&Ws[scol][sh]     = d0;
            *(uint4*)&Ws[scol][sh + 8] = d1;
            __syncthreads();
            if (kt + 32 < 128){
                d0 = *(const uint4*)(w2g + kt + 32);
                d1 = *(const uint4*)(w2g + kt + 40);
            }
            bf16x8 af[2], bfr[4];
            #pragma unroll
            for (int mi = 0; mi < 2; mi++) af[mi]  = *(const bf16x8*)&Hs[wr*32 + mi*16 + lr][kt + lk8];
            #pragma unroll
            for (int ni = 0; ni < 4; ni++) bfr[ni] = *(const bf16x8*)&Ws[wc*64 + ni*16 + lr][lk8];
            #pragma unroll
            for (int mi = 0; mi < 2; mi++)
                #pragma unroll
                for (int ni = 0; ni < 4; ni++)
                    acc2[mi][ni] = __builtin_amdgcn_mfma_f32_16x16x32_bf16(af[mi], bfr[ni], acc2[mi][ni], 0, 0, 0);
        }
        // ---- fused += gw[:,e] * (eo + b2) ----
        #pragma unroll
        for (int mi = 0; mi < 2; mi++)
            #pragma unroll
            for (int ni = 0; ni < 4; ni++){
                int col = wc*64 + ni*16 + lr;
                float b2v = exp_b2[e*128 + col];
                #pragma unroll
                for (int j = 0; j < 4; j++){
                    int row = wr*32 + mi*16 + r4 + j;
                    fus[mi][ni][j] += GW[row][e] * (acc2[mi][ni][j] + b2v);
                }
            }
    }

    __syncthreads();  // all Hs reads (expert 7 w2) done before overwrite
    #pragma unroll
    for (int mi = 0; mi < 2; mi++)
        #pragma unroll
        for (int ni = 0; ni < 4; ni++)
            #pragma unroll
            for (int j = 0; j < 4; j++)
                Hs[wr*32 + mi*16 + r4 + j][wc*64 + ni*16 + lr] = f2bf(fus[mi][ni][j]);

    // ---- penult = relu(fused @ pre_w + pre_b) : [64x128]x[128x64] ----
    // waves 2x2 over 64x64 output: 32x32 per wave
    f32x4 accp[2][2];
    #pragma unroll
    for (int i = 0; i < 2; i++)
        #pragma unroll
        for (int j = 0; j < 2; j++) accp[i][j] = {0.f, 0.f, 0.f, 0.f};
    uint4 p0, p1;
    const u16* pg = prwT + (size_t)scol*128 + sh;
    if (tid < 128){ p0 = *(const uint4*)(pg); p1 = *(const uint4*)(pg + 8); }
    for (int kt = 0; kt < 128; kt += 32){
        __syncthreads();  // orders Hs(fused) writes before reads; protects Ws
        if (tid < 128){
            *(uint4*)&Ws[scol][sh]     = p0;
            *(uint4*)&Ws[scol][sh + 8] = p1;
        }
        __syncthreads();
        if (tid < 128 && kt + 32 < 128){
            p0 = *(const uint4*)(pg + kt + 32);
            p1 = *(const uint4*)(pg + kt + 40);
        }
        bf16x8 af[2], bfr[2];
        #pragma unroll
        for (int mi = 0; mi < 2; mi++) af[mi]  = *(const bf16x8*)&Hs[wr*32 + mi*16 + lr][kt + lk8];
        #pragma unroll
        for (int ni = 0; ni < 2; ni++) bfr[ni] = *(const bf16x8*)&Ws[wc*32 + ni*16 + lr][lk8];
        #pragma unroll
        for (int mi = 0; mi < 2; mi++)
            #pragma unroll
            for (int ni = 0; ni < 2; ni++)
                accp[mi][ni] = __builtin_amdgcn_mfma_f32_16x16x32_bf16(af[mi], bfr[ni], accp[mi][ni], 0, 0, 0);
    }
    // penult (f32) into Xs region (x tile dead now)
    float* Pen = (float*)&Xs[0][0];   // [64][68]
    #pragma unroll
    for (int mi = 0; mi < 2; mi++)
        #pragma unroll
        for (int ni = 0; ni < 2; ni++){
            int col = wc*32 + ni*16 + lr;
            float pbv = pre_b[col];
            #pragma unroll
            for (int j = 0; j < 4; j++){
                int row = wr*32 + mi*16 + r4 + j;
                Pen[row*68 + col] = fmaxf(accp[mi][ni][j] + pbv, 0.f);
            }
        }
    __syncthreads();
    // ---- head ----
    if (tid < 128){
        int r = tid >> 1, c = tid & 1;
        float s = head_b[c];
        for (int k = 0; k < 64; k++) s += Pen[r*68 + k] * head_w[k*2 + c];
        out[(size_t)(row0 + r)*2 + c] = s;
    }
}

extern "C" void kernel_launch(void* const* d_in, const int* in_sizes, int n_in,
                              void* d_out, int out_size, void* d_ws, size_t ws_size,
                              hipStream_t stream) {
    const float* ft     = (const float*)d_in[0];
    const float* fa     = (const float*)d_in[1];
    const float* fv     = (const float*)d_in[2];
    const float* proj_w = (const float*)d_in[3];
    const float* proj_b = (const float*)d_in[4];
    const float* exp_w1 = (const float*)d_in[5];
    const float* exp_b1 = (const float*)d_in[6];
    const float* exp_w2 = (const float*)d_in[7];
    const float* exp_b2 = (const float*)d_in[8];
    const float* gate_w = (const float*)d_in[9];
    const float* gate_b = (const float*)d_in[10];
    const float* pre_w  = (const float*)d_in[11];
    const float* pre_b  = (const float*)d_in[12];
    const float* head_w = (const float*)d_in[13];
    const float* head_b = (const float*)d_in[14];
    float* out = (float*)d_out;

    u16* xq   = (u16*)d_ws;                       // 32768*384
    u16* pwT  = xq  + (size_t)B_ROWS * 384;       // 294912
    u16* w1T  = pwT + 294912;                     // 393216
    u16* w2T  = w1T + 393216;                     // 131072
    u16* prwT = w2T + 131072;                     // 8192
    u16* gwT  = prwT + 8192;                      // 3072

    cast_weights_kernel<<<3244, 256, 0, stream>>>(proj_w, exp_w1, exp_w2, pre_w, gate_w,
                                                  pwT, w1T, w2T, prwT, gwT);
    proj_kernel<<<dim3(B_ROWS/64, 3), 256, 0, stream>>>(ft, fa, fv, pwT, proj_b, xq);
    moe_kernel<<<B_ROWS/64, 256, 0, stream>>>(xq, w1T, w2T, prwT, gwT,
                                              gate_b, exp_b1, exp_b2,
                                              pre_b, head_w, head_b, out);
}

// Round 3
// 173.764 us; speedup vs baseline: 1.4020x; 1.4020x over previous
//
#include <hip/hip_runtime.h>
#include <hip/hip_bf16.h>

#define B_ROWS 32768

typedef unsigned short u16;
typedef unsigned int u32;
typedef float f32x4 __attribute__((ext_vector_type(4)));
typedef __bf16 bf16x8 __attribute__((ext_vector_type(8)));
typedef unsigned short u16x8 __attribute__((ext_vector_type(8)));

__device__ __forceinline__ u16 f2bf(float f){
    union { float f; u32 u; } v; v.f = f;
    return (u16)((v.u + 0x7FFFu + ((v.u >> 16) & 1u)) >> 16);
}
__device__ __forceinline__ float bf2f(u16 h){
    union { u32 u; float f; } v; v.u = ((u32)h) << 16; return v.f;
}
// v_cvt_pk_bf16_f32: dst.lo = bf16(lo), dst.hi = bf16(hi), RNE
__device__ __forceinline__ u32 cvtpk(float lo, float hi){
    u32 r;
    asm("v_cvt_pk_bf16_f32 %0, %1, %2" : "=v"(r) : "v"(lo), "v"(hi));
    return r;
}
__device__ __forceinline__ void async_cp16(void* lds_dst, const void* g_src){
    __builtin_amdgcn_global_load_lds(
        (const __attribute__((address_space(1))) unsigned int*)g_src,
        (__attribute__((address_space(3))) unsigned int*)lds_dst, 16, 0, 0);
}

// ---------------- weight cast/transpose ---------------------------------------
// pimg: per-modality, per-64k-chunk 16KB byte images of the proj-B LDS tile,
// XOR-swizzled (u16 idx: kb ^ ((col&7)<<3)) so a linear global_load_lds copy
// yields a bank-conflict-free [128 col][64 k] bf16 tile.
__global__ void cast_weights_kernel(const float* __restrict__ proj_w,
                                    const float* __restrict__ exp_w1,
                                    const float* __restrict__ exp_w2,
                                    const float* __restrict__ pre_w,
                                    const float* __restrict__ gate_w,
                                    u16* __restrict__ pimg, u16* __restrict__ w1T,
                                    u16* __restrict__ w2T, u16* __restrict__ prwT,
                                    u16* __restrict__ gwT){
    int i = blockIdx.x * 256 + threadIdx.x;
    if (i < 294912){                       // pimg [3][12][8192]
        int m = i / 98304, r = i % 98304;
        int c = r / 8192, rr = r % 8192;
        int col = rr >> 6, kb2 = rr & 63;
        int kb = kb2 ^ ((col & 7) << 3);
        pimg[i] = f2bf(proj_w[m*98304 + (c*64 + kb)*128 + col]);
    } else if (i < 688128){                // exp_w1T [8][128][384]
        int j = i - 294912;
        int e = j / 49152, r = j % 49152;
        int h = r / 384, k = r % 384;
        w1T[j] = f2bf(exp_w1[e*49152 + k*128 + h]);
    } else if (i < 819200){                // exp_w2T [8][128][128]
        int j = i - 688128;
        int e = j / 16384, r = j % 16384;
        int o = r / 128, k = r % 128;
        w2T[j] = f2bf(exp_w2[e*16384 + k*128 + o]);
    } else if (i < 827392){                // pre_wT [64][128]
        int j = i - 819200;
        int o = j / 128, k = j % 128;
        prwT[j] = f2bf(pre_w[k*64 + o]);
    } else if (i < 830464){                // gate_wT [8][384]
        int j = i - 827392;
        int e = j / 384, k = j % 384;
        gwT[j] = f2bf(gate_w[k*8 + e]);
    }
}

// ---------------- proj: tile 64 rows x 128 cols, BK=64, async dbuf ------------
// All staging via global_load_lds (zero staging VGPRs). A staged as raw f32
// with per-lane XOR-pre-swizzled SOURCE addresses (LDS dest stays linear);
// B staged from the pre-swizzled pimg. Counted vmcnt(8) keeps next chunk's 8
// DMA ops in flight across barriers.
__global__ __launch_bounds__(256, 2) void proj_kernel(
    const float* __restrict__ ft, const float* __restrict__ fa, const float* __restrict__ fv,
    const u16* __restrict__ pimg, const float* __restrict__ proj_b,
    u16* __restrict__ xq)
{
    __shared__ char lds[65536];            // 2 slots x (A 16KB + B 16KB)
    const int m = blockIdx.y;
    const float* feat = (m == 0) ? ft : (m == 1) ? fa : fv;
    const int row0 = blockIdx.x * 64;
    const int tid  = threadIdx.x;
    const int lane = tid & 63, wid = tid >> 6;
    const int wr = wid >> 1, wc = wid & 1;
    const int lr = lane & 15, q = lane >> 4, r4 = q * 4;

    // per-lane staging offsets (A source: XOR-pre-swizzled per-lane address)
    u32 aoffs[4];
    #pragma unroll
    for (int i = 0; i < 4; i++){
        int P = i*4096 + wid*1024 + lane*16;        // linear LDS byte pos
        int row = P >> 8, inner = P & 255;
        aoffs[i] = (u32)((row0 + row)*3072 + (inner ^ ((row & 7) << 4)));
    }
    const char* abase = (const char*)feat;
    const char* bbase = (const char*)pimg + (size_t)m * 196608 + wid*1024 + lane*16;
    const int ldsP = wid*1024 + lane*16;

    f32x4 acc[2][4];
    #pragma unroll
    for (int i = 0; i < 2; i++)
        #pragma unroll
        for (int j = 0; j < 4; j++) acc[i][j] = {0.f, 0.f, 0.f, 0.f};

#define STAGE(s, c) do{                                                        \
        char* la = lds + (s)*32768 + ldsP;                                     \
        char* lb = lds + (s)*32768 + 16384 + ldsP;                             \
        const char* gb = bbase + (c)*16384;                                    \
        u32 kadd = (u32)(c) << 8;                                              \
        _Pragma("unroll")                                                      \
        for (int i = 0; i < 4; i++) async_cp16(la + i*4096, abase + aoffs[i] + kadd); \
        _Pragma("unroll")                                                      \
        for (int i = 0; i < 4; i++) async_cp16(lb + i*4096, gb + i*4096);      \
    }while(0)

#define CONSUME(s) do{                                                         \
        const char* Abuf = lds + (s)*32768;                                    \
        const char* Bbuf = Abuf + 16384;                                       \
        _Pragma("unroll")                                                      \
        for (int ks = 0; ks < 2; ks++){                                        \
            bf16x8 af[2];                                                      \
            _Pragma("unroll")                                                  \
            for (int mi = 0; mi < 2; mi++){                                    \
                int row = wr*32 + mi*16 + lr;                                  \
                int aoff = row*256 + ((ks*128 + q*32) ^ ((row & 7) << 4));     \
                f32x4 a0 = *(const f32x4*)(Abuf + aoff);                       \
                f32x4 a1 = *(const f32x4*)(Abuf + (aoff ^ 16));                \
                union { u32 w[4]; bf16x8 v; } u;                               \
                u.w[0] = cvtpk(a0.x, a0.y); u.w[1] = cvtpk(a0.z, a0.w);        \
                u.w[2] = cvtpk(a1.x, a1.y); u.w[3] = cvtpk(a1.z, a1.w);        \
                af[mi] = u.v;                                                  \
            }                                                                  \
            _Pragma("unroll")                                                  \
            for (int ni = 0; ni < 4; ni++){                                    \
                int col = wc*64 + ni*16 + lr;                                  \
                int boff = col*128 + ((ks*64 + q*16) ^ ((col & 7) << 4));      \
                bf16x8 bf = *(const bf16x8*)(Bbuf + boff);                     \
                acc[0][ni] = __builtin_amdgcn_mfma_f32_16x16x32_bf16(af[0], bf, acc[0][ni], 0, 0, 0); \
                acc[1][ni] = __builtin_amdgcn_mfma_f32_16x16x32_bf16(af[1], bf, acc[1][ni], 0, 0, 0); \
            }                                                                  \
        }                                                                      \
    }while(0)

    STAGE(0, 0);
    int cur = 0;
    for (int t = 0; t < 11; t++){
        __builtin_amdgcn_sched_barrier(0);
        __builtin_amdgcn_s_barrier();                      // reads of slot cur^1 done (all waves)
        STAGE(cur ^ 1, t + 1);
        asm volatile("s_waitcnt vmcnt(8)" ::: "memory");   // chunk t landed (8 newest stay in flight)
        __builtin_amdgcn_s_barrier();                      // visible to all waves
        __builtin_amdgcn_sched_barrier(0);
        CONSUME(cur);
        cur ^= 1;
    }
    __builtin_amdgcn_sched_barrier(0);
    __builtin_amdgcn_s_barrier();
    asm volatile("s_waitcnt vmcnt(0)" ::: "memory");
    __builtin_amdgcn_s_barrier();
    __builtin_amdgcn_sched_barrier(0);
    CONSUME(cur);
#undef STAGE
#undef CONSUME

    // epilogue: stage bf16 tile in LDS, then coalesced 64B/lane stores
    __syncthreads();
    u16 (*Os)[136] = (u16(*)[136])lds;
    #pragma unroll
    for (int mi = 0; mi < 2; mi++)
        #pragma unroll
        for (int ni = 0; ni < 4; ni++){
            int col = wc*64 + ni*16 + lr;
            float bias = proj_b[m*128 + col];
            #pragma unroll
            for (int j = 0; j < 4; j++)
                Os[wr*32 + mi*16 + r4 + j][col] = f2bf(acc[mi][ni][j] + bias);
        }
    __syncthreads();
    {
        int row = tid >> 2, cg = (tid & 3) * 32;
        u16* dst = xq + (size_t)(row0 + row) * 384 + m*128 + cg;
        #pragma unroll
        for (int i = 0; i < 4; i++)
            *(uint4*)(dst + i*8) = *(uint4*)&Os[row][cg + i*8];
    }
}

// ---------------- fused gate + experts + pre + head ---------------------------
// grid (B/64), 256 threads = 4 waves (2x2). LDS ~78KB -> 2 blocks/CU.
__global__ __launch_bounds__(256, 2) void moe_kernel(
    const u16* __restrict__ xq,
    const u16* __restrict__ w1T, const u16* __restrict__ w2T, const u16* __restrict__ prwT,
    const u16* __restrict__ gwT, const float* __restrict__ gate_b,
    const float* __restrict__ exp_b1, const float* __restrict__ exp_b2,
    const float* __restrict__ pre_b, const float* __restrict__ head_w, const float* __restrict__ head_b,
    float* __restrict__ out)
{
    __shared__ u16  Xs[64][392];   // x tile, full K=384 (+8 pad)
    __shared__ u16  Ws[128][40];   // per-K-step weight staging
    __shared__ u16  Hs[64][136];   // h tile / fused tile (+8 pad)
    __shared__ float GW[64][8];    // gate weights

    const int row0 = blockIdx.x * 64;
    const int tid  = threadIdx.x;
    const int lane = tid & 63, wid = tid >> 6;
    const int wr = wid >> 1, wc = wid & 1;
    const int lr = lane & 15, lk8 = (lane >> 4) * 8, r4 = (lane >> 4) * 4;
    const int scol = tid >> 1, sh = (tid & 1) * 16;

    {   // load x tile: 4 threads per row, 96 cols each
        const int xr = tid >> 2, xc = (tid & 3) * 96;
        const u16* xg = xq + (size_t)(row0 + xr) * 384 + xc;
        #pragma unroll
        for (int i = 0; i < 12; i++)
            *(uint4*)&Xs[xr][xc + i*8] = *(const uint4*)(xg + i*8);
    }
    __syncthreads();

    // ---- gate logits + softmax ----
    for (int task = tid; task < 512; task += 256){
        int r = task >> 3, e = task & 7;
        float s = gate_b[e];
        const u16* gw = gwT + e * 384;
        for (int k = 0; k < 384; k += 8){
            u16x8 xv = *(const u16x8*)&Xs[r][k];
            u16x8 wv = *(const u16x8*)(gw + k);
            #pragma unroll
            for (int j = 0; j < 8; j++) s += bf2f(xv[j]) * bf2f(wv[j]);
        }
        GW[r][e] = s;
    }
    __syncthreads();
    if (tid < 64){
        float v[8], mx = -1e30f;
        #pragma unroll
        for (int e = 0; e < 8; e++){ v[e] = GW[tid][e]; mx = fmaxf(mx, v[e]); }
        float sum = 0.f;
        #pragma unroll
        for (int e = 0; e < 8; e++){ v[e] = __expf(v[e] - mx); sum += v[e]; }
        float inv = 1.f / sum;
        #pragma unroll
        for (int e = 0; e < 8; e++) GW[tid][e] = v[e] * inv;
    }
    // (GW consumed only after multiple barriers below)

    f32x4 fus[2][4];
    #pragma unroll
    for (int i = 0; i < 2; i++)
        #pragma unroll
        for (int j = 0; j < 4; j++) fus[i][j] = {0.f, 0.f, 0.f, 0.f};

    for (int e = 0; e < 8; e++){
        // ---- h = relu(x @ w1_e + b1) : [64x384]x[384x128] ----
        f32x4 acc[2][4];
        #pragma unroll
        for (int i = 0; i < 2; i++)
            #pragma unroll
            for (int j = 0; j < 4; j++) acc[i][j] = {0.f, 0.f, 0.f, 0.f};
        const u16* wg = w1T + (size_t)e*49152 + (size_t)scol*384 + sh;
        uint4 c0 = *(const uint4*)(wg);
        uint4 c1 = *(const uint4*)(wg + 8);
        for (int kt = 0; kt < 384; kt += 32){
            __syncthreads();
            *(uint4*)&Ws[scol][sh]     = c0;
            *(uint4*)&Ws[scol][sh + 8] = c1;
            __syncthreads();
            if (kt + 32 < 384){
                c0 = *(const uint4*)(wg + kt + 32);
                c1 = *(const uint4*)(wg + kt + 40);
            }
            bf16x8 af[2], bfr[4];
            #pragma unroll
            for (int mi = 0; mi < 2; mi++) af[mi]  = *(const bf16x8*)&Xs[wr*32 + mi*16 + lr][kt + lk8];
            #pragma unroll
            for (int ni = 0; ni < 4; ni++) bfr[ni] = *(const bf16x8*)&Ws[wc*64 + ni*16 + lr][lk8];
            #pragma unroll
            for (int mi = 0; mi < 2; mi++)
                #pragma unroll
                for (int ni = 0; ni < 4; ni++)
                    acc[mi][ni] = __builtin_amdgcn_mfma_f32_16x16x32_bf16(af[mi], bfr[ni], acc[mi][ni], 0, 0, 0);
        }
        // write h (relu, bf16)
        #pragma unroll
        for (int mi = 0; mi < 2; mi++)
            #pragma unroll
            for (int ni = 0; ni < 4; ni++){
                int col = wc*64 + ni*16 + lr;
                float b1v = exp_b1[e*128 + col];
                #pragma unroll
                for (int j = 0; j < 4; j++){
                    int row = wr*32 + mi*16 + r4 + j;
                    Hs[row][col] = f2bf(fmaxf(acc[mi][ni][j] + b1v, 0.f));
                }
            }
        // ---- eo = h @ w2_e + b2 : [64x128]x[128x128] ----
        f32x4 acc2[2][4];
        #pragma unroll
        for (int i = 0; i < 2; i++)
            #pragma unroll
            for (int j = 0; j < 4; j++) acc2[i][j] = {0.f, 0.f, 0.f, 0.f};
        const u16* w2g = w2T + (size_t)e*16384 + (size_t)scol*128 + sh;
        uint4 d0 = *(const uint4*)(w2g);
        uint4 d1 = *(const uint4*)(w2g + 8);
        for (int kt = 0; kt < 128; kt += 32){
            __syncthreads();   // also orders Hs writes before Hs reads
            *(uint4*)&Ws[scol][sh]     = d0;
            *(uint4*)&Ws[scol][sh + 8] = d1;
            __syncthreads();
            if (kt + 32 < 128){
                d0 = *(const uint4*)(w2g + kt + 32);
                d1 = *(const uint4*)(w2g + kt + 40);
            }
            bf16x8 af[2], bfr[4];
            #pragma unroll
            for (int mi = 0; mi < 2; mi++) af[mi]  = *(const bf16x8*)&Hs[wr*32 + mi*16 + lr][kt + lk8];
            #pragma unroll
            for (int ni = 0; ni < 4; ni++) bfr[ni] = *(const bf16x8*)&Ws[wc*64 + ni*16 + lr][lk8];
            #pragma unroll
            for (int mi = 0; mi < 2; mi++)
                #pragma unroll
                for (int ni = 0; ni < 4; ni++)
                    acc2[mi][ni] = __builtin_amdgcn_mfma_f32_16x16x32_bf16(af[mi], bfr[ni], acc2[mi][ni], 0, 0, 0);
        }
        // ---- fused += gw[:,e] * (eo + b2) ----
        #pragma unroll
        for (int mi = 0; mi < 2; mi++)
            #pragma unroll
            for (int ni = 0; ni < 4; ni++){
                int col = wc*64 + ni*16 + lr;
                float b2v = exp_b2[e*128 + col];
                #pragma unroll
                for (int j = 0; j < 4; j++){
                    int row = wr*32 + mi*16 + r4 + j;
                    fus[mi][ni][j] += GW[row][e] * (acc2[mi][ni][j] + b2v);
                }
            }
    }

    __syncthreads();  // all Hs reads (expert 7 w2) done before overwrite
    #pragma unroll
    for (int mi = 0; mi < 2; mi++)
        #pragma unroll
        for (int ni = 0; ni < 4; ni++)
            #pragma unroll
            for (int j = 0; j < 4; j++)
                Hs[wr*32 + mi*16 + r4 + j][wc*64 + ni*16 + lr] = f2bf(fus[mi][ni][j]);

    // ---- penult = relu(fused @ pre_w + pre_b) : [64x128]x[128x64] ----
    f32x4 accp[2][2];
    #pragma unroll
    for (int i = 0; i < 2; i++)
        #pragma unroll
        for (int j = 0; j < 2; j++) accp[i][j] = {0.f, 0.f, 0.f, 0.f};
    uint4 p0, p1;
    const u16* pg = prwT + (size_t)scol*128 + sh;
    if (tid < 128){ p0 = *(const uint4*)(pg); p1 = *(const uint4*)(pg + 8); }
    for (int kt = 0; kt < 128; kt += 32){
        __syncthreads();  // orders Hs(fused) writes before reads; protects Ws
        if (tid < 128){
            *(uint4*)&Ws[scol][sh]     = p0;
            *(uint4*)&Ws[scol][sh + 8] = p1;
        }
        __syncthreads();
        if (tid < 128 && kt + 32 < 128){
            p0 = *(const uint4*)(pg + kt + 32);
            p1 = *(const uint4*)(pg + kt + 40);
        }
        bf16x8 af[2], bfr[2];
        #pragma unroll
        for (int mi = 0; mi < 2; mi++) af[mi]  = *(const bf16x8*)&Hs[wr*32 + mi*16 + lr][kt + lk8];
        #pragma unroll
        for (int ni = 0; ni < 2; ni++) bfr[ni] = *(const bf16x8*)&Ws[wc*32 + ni*16 + lr][lk8];
        #pragma unroll
        for (int mi = 0; mi < 2; mi++)
            #pragma unroll
            for (int ni = 0; ni < 2; ni++)
                accp[mi][ni] = __builtin_amdgcn_mfma_f32_16x16x32_bf16(af[mi], bfr[ni], accp[mi][ni], 0, 0, 0);
    }
    // penult (f32) into Xs region (x tile dead now)
    float* Pen = (float*)&Xs[0][0];   // [64][68]
    #pragma unroll
    for (int mi = 0; mi < 2; mi++)
        #pragma unroll
        for (int ni = 0; ni < 2; ni++){
            int col = wc*32 + ni*16 + lr;
            float pbv = pre_b[col];
            #pragma unroll
            for (int j = 0; j < 4; j++){
                int row = wr*32 + mi*16 + r4 + j;
                Pen[row*68 + col] = fmaxf(accp[mi][ni][j] + pbv, 0.f);
            }
        }
    __syncthreads();
    // ---- head ----
    if (tid < 128){
        int r = tid >> 1, c = tid & 1;
        float s = head_b[c];
        for (int k = 0; k < 64; k++) s += Pen[r*68 + k] * head_w[k*2 + c];
        out[(size_t)(row0 + r)*2 + c] = s;
    }
}

extern "C" void kernel_launch(void* const* d_in, const int* in_sizes, int n_in,
                              void* d_out, int out_size, void* d_ws, size_t ws_size,
                              hipStream_t stream) {
    const float* ft     = (const float*)d_in[0];
    const float* fa     = (const float*)d_in[1];
    const float* fv     = (const float*)d_in[2];
    const float* proj_w = (const float*)d_in[3];
    const float* proj_b = (const float*)d_in[4];
    const float* exp_w1 = (const float*)d_in[5];
    const float* exp_b1 = (const float*)d_in[6];
    const float* exp_w2 = (const float*)d_in[7];
    const float* exp_b2 = (const float*)d_in[8];
    const float* gate_w = (const float*)d_in[9];
    const float* gate_b = (const float*)d_in[10];
    const float* pre_w  = (const float*)d_in[11];
    const float* pre_b  = (const float*)d_in[12];
    const float* head_w = (const float*)d_in[13];
    const float* head_b = (const float*)d_in[14];
    float* out = (float*)d_out;

    u16* xq   = (u16*)d_ws;                       // 32768*384
    u16* pimg = xq   + (size_t)B_ROWS * 384;      // 294912
    u16* w1T  = pimg + 294912;                    // 393216
    u16* w2T  = w1T + 393216;                     // 131072
    u16* prwT = w2T + 131072;                     // 8192
    u16* gwT  = prwT + 8192;                      // 3072

    cast_weights_kernel<<<3244, 256, 0, stream>>>(proj_w, exp_w1, exp_w2, pre_w, gate_w,
                                                  pimg, w1T, w2T, prwT, gwT);
    proj_kernel<<<dim3(B_ROWS/64, 3), 256, 0, stream>>>(ft, fa, fv, pimg, proj_b, xq);
    moe_kernel<<<B_ROWS/64, 256, 0, stream>>>(xq, w1T, w2T, prwT, gwT,
                                              gate_b, exp_b1, exp_b2,
                                              pre_b, head_w, head_b, out);
}